// Round 1
// baseline (1487.076 us; speedup 1.0000x reference)
//
#include <hip/hip_runtime.h>

#define E_TOTAL 500000
#define DN 128
#define CIN 384      // 2*DN + D_EDGE
#define DH 512
#define DOUT 128
#define MT 64        // edges per tile
#define NTILE 7813   // ceil(E/MT), last tile 32 valid edges
#define NPERS 512    // persistent blocks: 2 per CU (LDS-bound)
#define LDA 392      // sA leading dim (bf16): 384 + 8 pad
#define LDH 520      // sH leading dim (bf16): 512 + 8 pad

typedef short short8 __attribute__((ext_vector_type(8)));
typedef float f32x4 __attribute__((ext_vector_type(4)));

__device__ inline short f2bf(float f) {
    unsigned int u = __float_as_uint(f);
    u = (u + 0x7FFFu + ((u >> 16) & 1u)) >> 16;
    return (short)u;
}

// Coalesced 32x32 LDS tile transpose: W1 [384][512] -> w1t bf16 [512][384],
// W2 [512][128] -> w2t bf16 [128][512]. Grid: 192 + 64 = 256 blocks x 256 thr.
__global__ void prep_weights(const float* __restrict__ w1,
                             const float* __restrict__ w2,
                             short* __restrict__ w1t,
                             short* __restrict__ w2t) {
    __shared__ float t[32][33];
    int b = blockIdx.x;
    const float* src; short* dst; int R, C, tr, tc;
    if (b < 192) { src = w1; dst = w1t; R = 384; C = 512; tr = b >> 4; tc = b & 15; }
    else { b -= 192; src = w2; dst = w2t; R = 512; C = 128; tr = b >> 2; tc = b & 3; }
    int lx = threadIdx.x & 31, ly = threadIdx.x >> 5;   // 32 x 8
#pragma unroll
    for (int p = 0; p < 4; p++) {
        int r = tr * 32 + p * 8 + ly;
        t[p * 8 + ly][lx] = src[(size_t)r * C + tc * 32 + lx];
    }
    __syncthreads();
#pragma unroll
    for (int p = 0; p < 4; p++) {
        int c = tc * 32 + p * 8 + ly;                   // dst row = src col
        dst[(size_t)c * R + tr * 32 + lx] = f2bf(t[lx][p * 8 + ly]);
    }
}

// Persistent-block pipelined edge MLP.
// Per tile: GEMM1 | bar | epilogue->sH, preload w2t[0..3], ISSUE next-tile
// gather (12xfloat4 regs) + next-next idx | bar | GEMM2 + out | bar |
// gather regs -> sA | bar.  Barriers are raw s_barrier + lgkmcnt(0) ONLY, so
// the staged gather vmem loads stay in flight across them (they retire under
// GEMM2).  Both GEMMs use swapped operands (weights as A, data as B): same
// loads, transposed C layout -> vectorized ds_write_b64 epilogue and
// global_store_dwordx4 output.
__global__ __launch_bounds__(512, 4) void edge_mlp(
        const float* __restrict__ x,
        const int* __restrict__ ei,       // [2][E]
        const float* __restrict__ ea,
        const float* __restrict__ b1,
        const float* __restrict__ b2,
        const short* __restrict__ w1t,    // bf16 [512][384]
        const short* __restrict__ w2t,    // bf16 [128][512]
        float* __restrict__ out) {
    __shared__ short sBuf[MT * LDH];      // union: sA [64][392] / sH [64][520]
    __shared__ int sIdx[2][2][MT];        // double-buffered edge indices
    short (*sA)[LDA] = (short (*)[LDA])sBuf;
    short (*sH)[LDH] = (short (*)[LDH])sBuf;

    const int tid = threadIdx.x;
    const int wave = tid >> 6;            // 0..7
    const int lane = tid & 63;
    const int l16 = lane & 15;
    const int quad = lane >> 4;
    const int lane32 = tid & 31;
    const int g = tid >> 5;               // 0..15 gather group
    const int t0 = blockIdx.x;

    // loop-invariant biases (compiler keeps in regs or rematerializes)
    float4 b1v[4];
#pragma unroll
    for (int nt = 0; nt < 4; nt++)
        b1v[nt] = *reinterpret_cast<const float4*>(&b1[wave * 64 + nt * 16 + quad * 4]);
    float4 b2v = *reinterpret_cast<const float4*>(&b2[wave * 16 + quad * 4]);

    // ---- prologue: indices for tile0 (+ tile1), direct gather of tile0 ----
    if (tid < 2 * MT) {
        int rrow = tid >> 6, r = tid & 63;
        int e = t0 * MT + r; e = e < E_TOTAL ? e : E_TOTAL - 1;
        sIdx[0][rrow][r] = ei[rrow * E_TOTAL + e];
        if (t0 + NPERS < NTILE) {
            int e2 = (t0 + NPERS) * MT + r; e2 = e2 < E_TOTAL ? e2 : E_TOTAL - 1;
            sIdx[1][rrow][r] = ei[rrow * E_TOTAL + e2];
        }
    }
    __syncthreads();
#pragma unroll
    for (int j = 0; j < 12; j++) {        // seg = j>>2 uniform per j
        const int seg = j >> 2;
        const int r = g + 16 * (j & 3);
        const float* src;
        if (seg == 0)      src = x + (size_t)sIdx[0][0][r] * DN;
        else if (seg == 1) src = x + (size_t)sIdx[0][1][r] * DN;
        else { int e = t0 * MT + r; e = e < E_TOTAL ? e : E_TOTAL - 1; src = ea + (size_t)e * DN; }
        float4 v = reinterpret_cast<const float4*>(src)[lane32];
        short4 p; p.x = f2bf(v.x); p.y = f2bf(v.y); p.z = f2bf(v.z); p.w = f2bf(v.w);
        *reinterpret_cast<short4*>(&sA[r][seg * DN + lane32 * 4]) = p;
    }
    __syncthreads();

#pragma unroll 1
    for (int i = 0; ; i++) {
        const int t = t0 + i * NPERS;
        const int e0 = t * MT;
        const bool hasN1 = (t + NPERS) < NTILE;
        const bool hasN2 = (t + 2 * NPERS) < NTILE;

        // ---- GEMM1 (swapped): acc[nt][mt] holds hT tile ----
        f32x4 acc[4][4] = {};
        {
            const short* base1 = w1t + (size_t)(wave * 64 + l16) * CIN + quad * 8;
            short8 bb[4];
#pragma unroll
            for (int nt = 0; nt < 4; nt++)
                bb[nt] = *reinterpret_cast<const short8*>(base1 + nt * 16 * CIN);
            for (int k = 0; k < CIN; k += 32) {
                short8 bn[4];
                if (k + 32 < CIN) {
#pragma unroll
                    for (int nt = 0; nt < 4; nt++)
                        bn[nt] = *reinterpret_cast<const short8*>(base1 + nt * 16 * CIN + k + 32);
                }
                short8 a[4];
#pragma unroll
                for (int mt = 0; mt < 4; mt++)
                    a[mt] = *reinterpret_cast<const short8*>(&sA[mt * 16 + l16][k + quad * 8]);
#pragma unroll
                for (int nt = 0; nt < 4; nt++)
#pragma unroll
                    for (int mt = 0; mt < 4; mt++)
                        acc[nt][mt] = __builtin_amdgcn_mfma_f32_16x16x32_bf16(bb[nt], a[mt], acc[nt][mt], 0, 0, 0);
                if (k + 32 < CIN) {
#pragma unroll
                    for (int nt = 0; nt < 4; nt++) bb[nt] = bn[nt];
                }
            }
        }
        asm volatile("s_waitcnt lgkmcnt(0)" ::: "memory");   // sA reads done; NO vmcnt drain
        __builtin_amdgcn_s_barrier();

        // ---- epilogue: +b1, relu, bf16 -> sH via vector ds_write_b64 ----
        // lane holds 4 consecutive n at fixed m = mt*16+l16
#pragma unroll
        for (int nt = 0; nt < 4; nt++) {
#pragma unroll
            for (int mt = 0; mt < 4; mt++) {
                short4 p;
                p.x = f2bf(fmaxf(acc[nt][mt][0] + b1v[nt].x, 0.0f));
                p.y = f2bf(fmaxf(acc[nt][mt][1] + b1v[nt].y, 0.0f));
                p.z = f2bf(fmaxf(acc[nt][mt][2] + b1v[nt].z, 0.0f));
                p.w = f2bf(fmaxf(acc[nt][mt][3] + b1v[nt].w, 0.0f));
                *reinterpret_cast<short4*>(&sH[mt * 16 + l16][wave * 64 + nt * 16 + quad * 4]) = p;
            }
        }

        // ---- preload first w2t frags BEFORE gathers: GEMM2 k<4 retires
        //      independently of the (younger) gather loads ----
        const short* base2 = w2t + (size_t)(wave * 16 + l16) * DH + quad * 8;
        short8 b2f[4];
#pragma unroll
        for (int kk = 0; kk < 4; kk++)
            b2f[kk] = *reinterpret_cast<const short8*>(base2 + kk * 32);

        // ---- issue next-tile gather into regs; they land during GEMM2 ----
        float4 gv[12];
        if (hasN1) {
            const int* sI0 = sIdx[(i + 1) & 1][0];
            const int* sI1 = sIdx[(i + 1) & 1][1];
            const int e0n = (t + NPERS) * MT;
#pragma unroll
            for (int j = 0; j < 12; j++) {
                const int seg = j >> 2;
                const int r = g + 16 * (j & 3);
                const float* src;
                if (seg == 0)      src = x + (size_t)sI0[r] * DN;
                else if (seg == 1) src = x + (size_t)sI1[r] * DN;
                else { int e = e0n + r; e = e < E_TOTAL ? e : E_TOTAL - 1; src = ea + (size_t)e * DN; }
                gv[j] = reinterpret_cast<const float4*>(src)[lane32];
            }
        }
        int idxN = 0;
        if (hasN2 && tid < 2 * MT) {      // next-next tile indices, 2-deep pipe
            int rrow = tid >> 6, r = tid & 63;
            int e2 = (t + 2 * NPERS) * MT + r; e2 = e2 < E_TOTAL ? e2 : E_TOTAL - 1;
            idxN = ei[rrow * E_TOTAL + e2];
        }
        __builtin_amdgcn_sched_barrier(0);                   // pin issues before barrier
        asm volatile("s_waitcnt lgkmcnt(0)" ::: "memory");   // sH writes done; gathers stay in flight
        __builtin_amdgcn_s_barrier();

        // ---- GEMM2 (swapped): out^T tiles; vectorized float4 stores ----
        {
            f32x4 acc2[4] = {};
            short8 bw = b2f[0];
#pragma unroll
            for (int kk = 0; kk < 16; kk++) {
                short8 bnext = bw;
                if (kk < 3) bnext = b2f[kk + 1];
                else if (kk < 15) bnext = *reinterpret_cast<const short8*>(base2 + (kk + 1) * 32);
                short8 h[4];
#pragma unroll
                for (int mt = 0; mt < 4; mt++)
                    h[mt] = *reinterpret_cast<const short8*>(&sH[mt * 16 + l16][kk * 32 + quad * 8]);
#pragma unroll
                for (int mt = 0; mt < 4; mt++)
                    acc2[mt] = __builtin_amdgcn_mfma_f32_16x16x32_bf16(bw, h[mt], acc2[mt], 0, 0, 0);
                bw = bnext;
            }
#pragma unroll
            for (int mt = 0; mt < 4; mt++) {
                int e = e0 + mt * 16 + l16;
                if (e < E_TOTAL) {
                    float4 o;
                    o.x = acc2[mt][0] + b2v.x;
                    o.y = acc2[mt][1] + b2v.y;
                    o.z = acc2[mt][2] + b2v.z;
                    o.w = acc2[mt][3] + b2v.w;
                    *reinterpret_cast<float4*>(&out[(size_t)e * DOUT + wave * 16 + quad * 4]) = o;
                }
            }
        }

        if (!hasN1) break;

        asm volatile("s_waitcnt lgkmcnt(0)" ::: "memory");   // sH reads done; stores NOT drained
        __builtin_amdgcn_s_barrier();

        // ---- staged gather regs -> sA (compiler inserts the vmcnt wait here) ----
#pragma unroll
        for (int j = 0; j < 12; j++) {
            const int seg = j >> 2;
            const int r = g + 16 * (j & 3);
            short4 p;
            p.x = f2bf(gv[j].x); p.y = f2bf(gv[j].y); p.z = f2bf(gv[j].z); p.w = f2bf(gv[j].w);
            *reinterpret_cast<short4*>(&sA[r][seg * DN + lane32 * 4]) = p;
        }
        if (hasN2 && tid < 2 * MT)
            sIdx[i & 1][tid >> 6][tid & 63] = idxN;
        asm volatile("s_waitcnt lgkmcnt(0)" ::: "memory");   // sA/sIdx writes done
        __builtin_amdgcn_s_barrier();
    }
}

extern "C" void kernel_launch(void* const* d_in, const int* in_sizes, int n_in,
                              void* d_out, int out_size, void* d_ws, size_t ws_size,
                              hipStream_t stream) {
    const float* x  = (const float*)d_in[0];
    const int*   ei = (const int*)d_in[1];
    const float* ea = (const float*)d_in[2];
    const float* W1 = (const float*)d_in[3];
    const float* b1 = (const float*)d_in[4];
    const float* W2 = (const float*)d_in[5];
    const float* b2 = (const float*)d_in[6];
    float* outp = (float*)d_out;

    short* w1t = (short*)d_ws;            // 512*384*2 = 384 KB
    short* w2t = w1t + DH * CIN;          // 128*512*2 = 128 KB

    prep_weights<<<256, 256, 0, stream>>>(W1, W2, w1t, w2t);
    edge_mlp<<<NPERS, 512, 0, stream>>>(x, ei, ea, b1, b2, w1t, w2t, outp);
}

// Round 2
// 1200.442 us; speedup vs baseline: 1.2388x; 1.2388x over previous
//
#include <hip/hip_runtime.h>

#define E_TOTAL 500000
#define N_NODES 50000
#define DN 128
#define CIN 384      // 2*DN + D_EDGE
#define DH 512
#define DOUT 128
#define MT 64        // edges per tile
#define NTILE 7813   // ceil(E/MT)
#define LDA 392      // sA leading dim (bf16): 384 + 8 pad (row step 4 banks, 2-way max)
#define LDH 520      // fallback kernel's sH leading dim
#define LDH2 536     // gemm2k sH leading dim: 1072B row = 16B-aligned, step 12 banks -> 2-way max

typedef short short8 __attribute__((ext_vector_type(8)));
typedef float f32x4 __attribute__((ext_vector_type(4)));

__device__ inline short f2bf(float f) {
    unsigned int u = __float_as_uint(f);
    u = (u + 0x7FFFu + ((u >> 16) & 1u)) >> 16;
    return (short)u;
}

// Coalesced 32x32 LDS tile transpose: W1 [384][512] -> w1t bf16 [512][384],
// W2 [512][128] -> w2t bf16 [128][512]. Grid: 192 + 64 = 256 blocks x 256 thr.
__global__ void prep_weights(const float* __restrict__ w1,
                             const float* __restrict__ w2,
                             short* __restrict__ w1t,
                             short* __restrict__ w2t) {
    __shared__ float t[32][33];
    int b = blockIdx.x;
    const float* src; short* dst; int R, C, tr, tc;
    if (b < 192) { src = w1; dst = w1t; R = 384; C = 512; tr = b >> 4; tc = b & 15; }
    else { b -= 192; src = w2; dst = w2t; R = 512; C = 128; tr = b >> 2; tc = b & 3; }
    int lx = threadIdx.x & 31, ly = threadIdx.x >> 5;   // 32 x 8
#pragma unroll
    for (int p = 0; p < 4; p++) {
        int r = tr * 32 + p * 8 + ly;
        t[p * 8 + ly][lx] = src[(size_t)r * C + tc * 32 + lx];
    }
    __syncthreads();
#pragma unroll
    for (int p = 0; p < 4; p++) {
        int c = tc * 32 + p * 8 + ly;                   // dst row = src col
        dst[(size_t)c * R + tr * 32 + lx] = f2bf(t[lx][p * 8 + ly]);
    }
}

// x f32 [50000][128] -> bf16. 3125 blocks x 256 thr x 8 elems = 6.4M exact.
__global__ void cvt_x(const float* __restrict__ x, short* __restrict__ xb) {
    int i = blockIdx.x * 256 + threadIdx.x;
    const float4* s = reinterpret_cast<const float4*>(x) + (size_t)i * 2;
    float4 a = s[0], b = s[1];
    short8 p;
    p[0] = f2bf(a.x); p[1] = f2bf(a.y); p[2] = f2bf(a.z); p[3] = f2bf(a.w);
    p[4] = f2bf(b.x); p[5] = f2bf(b.y); p[6] = f2bf(b.z); p[7] = f2bf(b.w);
    reinterpret_cast<short8*>(xb)[i] = p;
}

// ---- Kernel A: gather + GEMM1 -> h (bf16, batch-local). Two barriers only.
// Swapped operands: acc[nt][mt] holds h^T fragment; lane l16 = edge row,
// quad*4+r = k cols -> short4 stores of h[e][k] (8B/lane).
__global__ __launch_bounds__(512, 4) void gemm1_gather(
        const short* __restrict__ xb,     // bf16 [N_NODES][128]
        const int* __restrict__ ei,       // [2][E]
        const float* __restrict__ ea,
        const float* __restrict__ b1,
        const short* __restrict__ w1t,    // bf16 [512][384]
        short* __restrict__ h,            // bf16 [tiles*64][512] batch-local
        int e_base) {
    __shared__ short sA[MT][LDA];
    __shared__ int sIdx[2][MT];
    const int tid = threadIdx.x;
    const int wave = tid >> 6, lane = tid & 63;
    const int l16 = lane & 15, quad = lane >> 4;
    const int lane32 = tid & 31, g = tid >> 5;
    const int e0 = e_base + blockIdx.x * MT;

    if (tid < 2 * MT) {
        int rr = tid >> 6, r = tid & 63;
        int e = e0 + r; e = e < E_TOTAL ? e : E_TOTAL - 1;
        sIdx[rr][r] = ei[rr * E_TOTAL + e];
    }
    __syncthreads();

    // gather: x segs are bf16 (8B/lane), ea seg f32->bf16 (16B/lane + cvt)
    for (int u = g; u < 3 * MT; u += 16) {   // 12 iters, seg uniform per iter
        int seg = u >> 6, r = u & 63;
        if (seg < 2) {
            const short* src = xb + (size_t)sIdx[seg][r] * DN;
            short4 v = reinterpret_cast<const short4*>(src)[lane32];
            *reinterpret_cast<short4*>(&sA[r][seg * DN + lane32 * 4]) = v;
        } else {
            int e = e0 + r; e = e < E_TOTAL ? e : E_TOTAL - 1;
            float4 v = reinterpret_cast<const float4*>(ea + (size_t)e * DN)[lane32];
            short4 p; p.x = f2bf(v.x); p.y = f2bf(v.y); p.z = f2bf(v.z); p.w = f2bf(v.w);
            *reinterpret_cast<short4*>(&sA[r][2 * DN + lane32 * 4]) = p;
        }
    }
    __syncthreads();

    f32x4 acc[4][4] = {};                 // [nt][mt]
    {
        const short* base1 = w1t + (size_t)(wave * 64 + l16) * CIN + quad * 8;
        short8 bb[4];
#pragma unroll
        for (int nt = 0; nt < 4; nt++)
            bb[nt] = *reinterpret_cast<const short8*>(base1 + nt * 16 * CIN);
        for (int k = 0; k < CIN; k += 32) {
            short8 bn[4];
            if (k + 32 < CIN) {
#pragma unroll
                for (int nt = 0; nt < 4; nt++)
                    bn[nt] = *reinterpret_cast<const short8*>(base1 + nt * 16 * CIN + k + 32);
            }
            short8 a[4];
#pragma unroll
            for (int mt = 0; mt < 4; mt++)
                a[mt] = *reinterpret_cast<const short8*>(&sA[mt * 16 + l16][k + quad * 8]);
#pragma unroll
            for (int nt = 0; nt < 4; nt++)
#pragma unroll
                for (int mt = 0; mt < 4; mt++)
                    acc[nt][mt] = __builtin_amdgcn_mfma_f32_16x16x32_bf16(bb[nt], a[mt], acc[nt][mt], 0, 0, 0);
            if (k + 32 < CIN) {
#pragma unroll
                for (int nt = 0; nt < 4; nt++) bb[nt] = bn[nt];
            }
        }
    }
    // epilogue: +b1, relu, bf16 -> h (global, batch-local rows; tail rows are
    // in-buffer garbage rows, never read as valid output)
    float4 b1v[4];
#pragma unroll
    for (int nt = 0; nt < 4; nt++)
        b1v[nt] = *reinterpret_cast<const float4*>(&b1[wave * 64 + nt * 16 + quad * 4]);
    short* hb = h + (size_t)blockIdx.x * MT * DH;
#pragma unroll
    for (int nt = 0; nt < 4; nt++) {
#pragma unroll
        for (int mt = 0; mt < 4; mt++) {
            short4 p;
            p.x = f2bf(fmaxf(acc[nt][mt][0] + b1v[nt].x, 0.0f));
            p.y = f2bf(fmaxf(acc[nt][mt][1] + b1v[nt].y, 0.0f));
            p.z = f2bf(fmaxf(acc[nt][mt][2] + b1v[nt].z, 0.0f));
            p.w = f2bf(fmaxf(acc[nt][mt][3] + b1v[nt].w, 0.0f));
            *reinterpret_cast<short4*>(hb + (size_t)(mt * 16 + l16) * DH
                                       + wave * 64 + nt * 16 + quad * 4) = p;
        }
    }
}

// ---- Kernel B: h tile -> LDS -> GEMM2 -> out. One barrier. Streaming.
__global__ __launch_bounds__(512, 4) void gemm2k(
        const short* __restrict__ h,      // bf16 batch-local
        const float* __restrict__ b2,
        const short* __restrict__ w2t,    // bf16 [128][512]
        float* __restrict__ out,
        int e_base) {
    __shared__ short sH[MT][LDH2];
    const int tid = threadIdx.x;
    const int wave = tid >> 6, lane = tid & 63;
    const int l16 = lane & 15, quad = lane >> 4;
    const int e0 = e_base + blockIdx.x * MT;
    const short* hb = h + (size_t)blockIdx.x * MT * DH;

    {   // stage 64KB: thread t -> row t>>3, 8x16B; per instr 8 rows x 128B contiguous
        int r = tid >> 3, c = (tid & 7) * 8;
#pragma unroll
        for (int j = 0; j < 8; j++) {
            short8 v = *reinterpret_cast<const short8*>(hb + (size_t)r * DH + c + j * 64);
            *reinterpret_cast<short8*>(&sH[r][c + j * 64]) = v;
        }
    }
    __syncthreads();

    f32x4 acc2[4] = {};
    const short* base2 = w2t + (size_t)(wave * 16 + l16) * DH + quad * 8;
    short8 bw = *reinterpret_cast<const short8*>(base2);
#pragma unroll
    for (int kk = 0; kk < 16; kk++) {
        short8 bn = bw;
        if (kk < 15) bn = *reinterpret_cast<const short8*>(base2 + (kk + 1) * 32);
        short8 hf[4];
#pragma unroll
        for (int mt = 0; mt < 4; mt++)
            hf[mt] = *reinterpret_cast<const short8*>(&sH[mt * 16 + l16][kk * 32 + quad * 8]);
#pragma unroll
        for (int mt = 0; mt < 4; mt++)
            acc2[mt] = __builtin_amdgcn_mfma_f32_16x16x32_bf16(bw, hf[mt], acc2[mt], 0, 0, 0);
        bw = bn;
    }
    float4 b2v = *reinterpret_cast<const float4*>(&b2[wave * 16 + quad * 4]);
#pragma unroll
    for (int mt = 0; mt < 4; mt++) {
        int e = e0 + mt * 16 + l16;
        if (e < E_TOTAL) {
            float4 o;
            o.x = acc2[mt][0] + b2v.x;
            o.y = acc2[mt][1] + b2v.y;
            o.z = acc2[mt][2] + b2v.z;
            o.w = acc2[mt][3] + b2v.w;
            *reinterpret_cast<float4*>(&out[(size_t)e * DOUT + wave * 16 + quad * 4]) = o;
        }
    }
}

// ---- Fallback: round-0 verified fused kernel (703us) if workspace too small.
__global__ __launch_bounds__(512, 4) void edge_mlp(
        const float* __restrict__ x,
        const int* __restrict__ ei,
        const float* __restrict__ ea,
        const float* __restrict__ b1,
        const float* __restrict__ b2,
        const short* __restrict__ w1t,
        const short* __restrict__ w2t,
        float* __restrict__ out) {
    __shared__ short sBuf[MT * LDH];
    __shared__ int sIdx[2][MT];
    short (*sA)[LDA] = (short (*)[LDA])sBuf;
    short (*sH)[LDH] = (short (*)[LDH])sBuf;
    const int tid = threadIdx.x;
    const int wave = tid >> 6;
    const int lane = tid & 63;
    const int l16 = lane & 15;
    const int quad = lane >> 4;
    const int e0 = blockIdx.x * MT;
    if (tid < MT) {
        int e = e0 + tid; e = e < E_TOTAL ? e : E_TOTAL - 1;
        sIdx[0][tid] = ei[e];
    } else if (tid < 2 * MT) {
        int r = tid - MT;
        int e = e0 + r; e = e < E_TOTAL ? e : E_TOTAL - 1;
        sIdx[1][r] = ei[E_TOTAL + e];
    }
    __syncthreads();
    {
        const int lane32 = tid & 31;
        const int g = tid >> 5;
        for (int u = g; u < 3 * MT; u += 16) {
            int seg = u >> 6;
            int r = u & 63;
            const float* src;
            if (seg == 0)      src = x + (size_t)sIdx[0][r] * DN;
            else if (seg == 1) src = x + (size_t)sIdx[1][r] * DN;
            else {
                int e = e0 + r; e = e < E_TOTAL ? e : E_TOTAL - 1;
                src = ea + (size_t)e * DN;
            }
            float4 v = reinterpret_cast<const float4*>(src)[lane32];
            short4 p;
            p.x = f2bf(v.x); p.y = f2bf(v.y); p.z = f2bf(v.z); p.w = f2bf(v.w);
            *reinterpret_cast<short4*>(&sA[r][seg * DN + lane32 * 4]) = p;
        }
    }
    __syncthreads();
    f32x4 acc[4][4] = {};
    {
        const int nb = wave * 64;
        const short* base = w1t + (size_t)(nb + l16) * CIN + quad * 8;
        short8 bb[4];
#pragma unroll
        for (int nt = 0; nt < 4; nt++)
            bb[nt] = *reinterpret_cast<const short8*>(base + nt * 16 * CIN);
        for (int k = 0; k < CIN; k += 32) {
            short8 bn[4];
            if (k + 32 < CIN) {
#pragma unroll
                for (int nt = 0; nt < 4; nt++)
                    bn[nt] = *reinterpret_cast<const short8*>(base + nt * 16 * CIN + k + 32);
            }
            short8 a[4];
#pragma unroll
            for (int mt = 0; mt < 4; mt++)
                a[mt] = *reinterpret_cast<const short8*>(&sA[mt * 16 + l16][k + quad * 8]);
#pragma unroll
            for (int nt = 0; nt < 4; nt++)
#pragma unroll
                for (int mt = 0; mt < 4; mt++)
                    acc[mt][nt] = __builtin_amdgcn_mfma_f32_16x16x32_bf16(a[mt], bb[nt], acc[mt][nt], 0, 0, 0);
            if (k + 32 < CIN) {
#pragma unroll
                for (int nt = 0; nt < 4; nt++) bb[nt] = bn[nt];
            }
        }
        __syncthreads();
#pragma unroll
        for (int nt = 0; nt < 4; nt++) {
            int n = wave * 64 + nt * 16 + l16;
            float bias = b1[n];
#pragma unroll
            for (int mt = 0; mt < 4; mt++)
#pragma unroll
                for (int r = 0; r < 4; r++) {
                    int m = mt * 16 + quad * 4 + r;
                    sH[m][n] = f2bf(fmaxf(acc[mt][nt][r] + bias, 0.0f));
                }
        }
    }
    __syncthreads();
    {
        f32x4 acc2[4] = {};
        const int n = wave * 16 + l16;
        const short* base2 = w2t + (size_t)n * DH + quad * 8;
        short8 bb = *reinterpret_cast<const short8*>(base2);
        for (int k = 0; k < DH; k += 32) {
            short8 bn;
            if (k + 32 < DH)
                bn = *reinterpret_cast<const short8*>(base2 + k + 32);
            short8 hh[4];
#pragma unroll
            for (int mt = 0; mt < 4; mt++)
                hh[mt] = *reinterpret_cast<const short8*>(&sH[mt * 16 + l16][k + quad * 8]);
#pragma unroll
            for (int mt = 0; mt < 4; mt++)
                acc2[mt] = __builtin_amdgcn_mfma_f32_16x16x32_bf16(hh[mt], bb, acc2[mt], 0, 0, 0);
            if (k + 32 < DH) bb = bn;
        }
        float bias = b2[n];
#pragma unroll
        for (int mt = 0; mt < 4; mt++)
#pragma unroll
            for (int r = 0; r < 4; r++) {
                int m = mt * 16 + quad * 4 + r;
                int e = e0 + m;
                if (e < E_TOTAL)
                    out[(size_t)e * DOUT + n] = acc2[mt][r] + bias;
            }
    }
}

extern "C" void kernel_launch(void* const* d_in, const int* in_sizes, int n_in,
                              void* d_out, int out_size, void* d_ws, size_t ws_size,
                              hipStream_t stream) {
    const float* x  = (const float*)d_in[0];
    const int*   ei = (const int*)d_in[1];
    const float* ea = (const float*)d_in[2];
    const float* W1 = (const float*)d_in[3];
    const float* b1 = (const float*)d_in[4];
    const float* W2 = (const float*)d_in[5];
    const float* b2 = (const float*)d_in[6];
    float* outp = (float*)d_out;

    short* w1t = (short*)d_ws;                    // 384 KB
    short* w2t = w1t + DH * CIN;                  // 128 KB
    prep_weights<<<256, 256, 0, stream>>>(W1, W2, w1t, w2t);

    const size_t base_bytes = (size_t)(DH * CIN + DOUT * DH) * 2;   // 512 KB
    const size_t xb_bytes = (size_t)N_NODES * DN * 2;               // 12.8 MB
    int nb = 0; size_t tiles_pb = 0;
    for (int cand = 1; cand <= 8; cand <<= 1) {
        size_t tpb = (NTILE + cand - 1) / cand;
        size_t need = base_bytes + xb_bytes + tpb * (size_t)MT * DH * 2;
        if (need <= ws_size) { nb = cand; tiles_pb = tpb; break; }
    }

    if (nb == 0) {   // workspace too small for split path
        edge_mlp<<<NTILE, 512, 0, stream>>>(x, ei, ea, b1, b2, w1t, w2t, outp);
        return;
    }

    short* xb = w2t + DOUT * DH;
    short* hbuf = xb + (size_t)N_NODES * DN;
    cvt_x<<<3125, 256, 0, stream>>>(x, xb);

    int tiles_done = 0;
    for (int b = 0; b < nb && tiles_done < NTILE; b++) {
        int tiles = (int)tiles_pb;
        if (tiles_done + tiles > NTILE) tiles = NTILE - tiles_done;
        gemm1_gather<<<tiles, 512, 0, stream>>>(xb, ei, ea, b1, w1t, hbuf, tiles_done * MT);
        gemm2k<<<tiles, 512, 0, stream>>>(hbuf, b2, w2t, outp, tiles_done * MT);
        tiles_done += tiles;
    }
}

// Round 3
// 964.062 us; speedup vs baseline: 1.5425x; 1.2452x over previous
//
#include <hip/hip_runtime.h>

#define E_TOTAL 500000
#define N_NODES 50000
#define DN 128
#define CIN 384      // 2*DN + D_EDGE
#define DH 512
#define DOUT 128
#define MT 64        // edges per block
#define NTILE 7813   // ceil(E/MT), last block 32 valid edges
#define LDA 392      // sA leading dim (bf16): 784B row = 196 dw = 4 mod 32 -> 2-way max per quarter-wave
#define LDH 520      // sH leading dim (bf16): 1040B row = 260 dw = 4 mod 32 -> 2-way max per quarter-wave

typedef short short8 __attribute__((ext_vector_type(8)));
typedef float f32x4 __attribute__((ext_vector_type(4)));

__device__ inline short f2bf(float f) {
    unsigned int u = __float_as_uint(f);
    u = (u + 0x7FFFu + ((u >> 16) & 1u)) >> 16;
    return (short)u;
}

// Coalesced 32x32 LDS tile transpose: W1 [384][512] -> w1t bf16 [512][384],
// W2 [512][128] -> w2t bf16 [128][512]. Grid: 192 + 64 = 256 blocks x 256 thr.
__global__ void prep_weights(const float* __restrict__ w1,
                             const float* __restrict__ w2,
                             short* __restrict__ w1t,
                             short* __restrict__ w2t) {
    __shared__ float t[32][33];
    int b = blockIdx.x;
    const float* src; short* dst; int R, C, tr, tc;
    if (b < 192) { src = w1; dst = w1t; R = 384; C = 512; tr = b >> 4; tc = b & 15; }
    else { b -= 192; src = w2; dst = w2t; R = 512; C = 128; tr = b >> 2; tc = b & 3; }
    int lx = threadIdx.x & 31, ly = threadIdx.x >> 5;   // 32 x 8
#pragma unroll
    for (int p = 0; p < 4; p++) {
        int r = tr * 32 + p * 8 + ly;
        t[p * 8 + ly][lx] = src[(size_t)r * C + tc * 32 + lx];
    }
    __syncthreads();
#pragma unroll
    for (int p = 0; p < 4; p++) {
        int c = tc * 32 + p * 8 + ly;                   // dst row = src col
        dst[(size_t)c * R + tr * 32 + lx] = f2bf(t[lx][p * 8 + ly]);
    }
}

// x f32 [50000][128] -> bf16. 3125 blocks x 256 thr x 8 elems = 6.4M exact.
__global__ void cvt_x(const float* __restrict__ x, short* __restrict__ xb) {
    int i = blockIdx.x * 256 + threadIdx.x;
    const float4* s = reinterpret_cast<const float4*>(x) + (size_t)i * 2;
    float4 a = s[0], b = s[1];
    short8 p;
    p[0] = f2bf(a.x); p[1] = f2bf(a.y); p[2] = f2bf(a.z); p[3] = f2bf(a.w);
    p[4] = f2bf(b.x); p[5] = f2bf(b.y); p[6] = f2bf(b.z); p[7] = f2bf(b.w);
    reinterpret_cast<short8*>(xb)[i] = p;
}

// Fused edge MLP, r0 skeleton + r2-verified pieces:
//  - batch-issued gather (all 12 global loads in regs -> 1 exposed latency),
//    x as bf16 (8B/lane) from pre-converted xb
//  - swapped GEMM1 (acc[nt][mt] = h^T frag) -> vector ds_write_b64 epilogue
//  - swapped GEMM2 -> float4 out stores, fully 64B-line-coalesced
//  - w1t/w2t first fragments prefetched into barrier shadows
__global__ __launch_bounds__(512, 4) void edge_mlp(
        const short* __restrict__ xb,     // bf16 [N_NODES][128] (may be null)
        const float* __restrict__ xf,     // f32 fallback when xb == null
        const int* __restrict__ ei,       // [2][E]
        const float* __restrict__ ea,
        const float* __restrict__ b1,
        const float* __restrict__ b2,
        const short* __restrict__ w1t,    // bf16 [512][384]
        const short* __restrict__ w2t,    // bf16 [128][512]
        float* __restrict__ out) {
    // sA [MT][LDA] (49KB) and sH [MT][LDH] (65KB) UNION: sA dead after GEMM1.
    __shared__ short sBuf[MT * LDH];
    __shared__ int sIdx[2][MT];
    short (*sA)[LDA] = (short (*)[LDA])sBuf;
    short (*sH)[LDH] = (short (*)[LDH])sBuf;

    const int tid = threadIdx.x;
    const int wave = tid >> 6;            // 0..7
    const int lane = tid & 63;
    const int l16 = lane & 15;
    const int quad = lane >> 4;
    const int lane32 = tid & 31;
    const int g = tid >> 5;               // 0..15 gather group
    const int e0 = blockIdx.x * MT;

    if (tid < 2 * MT) {
        int rr = tid >> 6, r = tid & 63;
        int e = e0 + r; e = e < E_TOTAL ? e : E_TOTAL - 1;
        sIdx[rr][r] = ei[rr * E_TOTAL + e];
    }
    __syncthreads();

    // ---- batch gather: issue ALL loads, then all converts/stores.
    // Transient regs (~32 VGPR) die before acc is materialized -> no spill.
    short4 gx[8];
    float4 ge[4];
    if (xb) {
#pragma unroll
        for (int j = 0; j < 4; j++) {
            int r = g + 16 * j;
            gx[j]     = reinterpret_cast<const short4*>(xb + (size_t)sIdx[0][r] * DN)[lane32];
            gx[4 + j] = reinterpret_cast<const short4*>(xb + (size_t)sIdx[1][r] * DN)[lane32];
            int e = e0 + r; e = e < E_TOTAL ? e : E_TOTAL - 1;
            ge[j] = reinterpret_cast<const float4*>(ea + (size_t)e * DN)[lane32];
        }
    } else {
#pragma unroll
        for (int j = 0; j < 4; j++) {
            int r = g + 16 * j;
            float4 v0 = reinterpret_cast<const float4*>(xf + (size_t)sIdx[0][r] * DN)[lane32];
            float4 v1 = reinterpret_cast<const float4*>(xf + (size_t)sIdx[1][r] * DN)[lane32];
            short4 p0, p1;
            p0.x = f2bf(v0.x); p0.y = f2bf(v0.y); p0.z = f2bf(v0.z); p0.w = f2bf(v0.w);
            p1.x = f2bf(v1.x); p1.y = f2bf(v1.y); p1.z = f2bf(v1.z); p1.w = f2bf(v1.w);
            gx[j] = p0; gx[4 + j] = p1;
            int e = e0 + r; e = e < E_TOTAL ? e : E_TOTAL - 1;
            ge[j] = reinterpret_cast<const float4*>(ea + (size_t)e * DN)[lane32];
        }
    }
    // prefetch first w1t fragments while gathers are in flight
    const short* base1 = w1t + (size_t)(wave * 64 + l16) * CIN + quad * 8;
    short8 bb[4];
#pragma unroll
    for (int nt = 0; nt < 4; nt++)
        bb[nt] = *reinterpret_cast<const short8*>(base1 + nt * 16 * CIN);
    // note: xb-path gx loads are 8B/lane; f32 path converted above
#pragma unroll
    for (int j = 0; j < 4; j++) {
        int r = g + 16 * j;
        *reinterpret_cast<short4*>(&sA[r][0 * DN + lane32 * 4]) = gx[j];
        *reinterpret_cast<short4*>(&sA[r][1 * DN + lane32 * 4]) = gx[4 + j];
        short4 p;
        p.x = f2bf(ge[j].x); p.y = f2bf(ge[j].y); p.z = f2bf(ge[j].z); p.w = f2bf(ge[j].w);
        *reinterpret_cast<short4*>(&sA[r][2 * DN + lane32 * 4]) = p;
    }
    __syncthreads();

    // ---- GEMM1 (swapped): acc[nt][mt] holds h^T fragment ----
    f32x4 acc[4][4] = {};
    for (int k = 0; k < CIN; k += 32) {
        short8 bn[4];
        if (k + 32 < CIN) {
#pragma unroll
            for (int nt = 0; nt < 4; nt++)
                bn[nt] = *reinterpret_cast<const short8*>(base1 + nt * 16 * CIN + k + 32);
        }
        short8 a[4];
#pragma unroll
        for (int mt = 0; mt < 4; mt++)
            a[mt] = *reinterpret_cast<const short8*>(&sA[mt * 16 + l16][k + quad * 8]);
#pragma unroll
        for (int nt = 0; nt < 4; nt++)
#pragma unroll
            for (int mt = 0; mt < 4; mt++)
                acc[nt][mt] = __builtin_amdgcn_mfma_f32_16x16x32_bf16(bb[nt], a[mt], acc[nt][mt], 0, 0, 0);
        if (k + 32 < CIN) {
#pragma unroll
            for (int nt = 0; nt < 4; nt++) bb[nt] = bn[nt];
        }
    }

    // prefetch first w2t fragment + biases into the barrier/epilogue shadow
    const short* base2 = w2t + (size_t)(wave * 16 + l16) * DH + quad * 8;
    short8 bw = *reinterpret_cast<const short8*>(base2);
    float4 b1v[4];
#pragma unroll
    for (int nt = 0; nt < 4; nt++)
        b1v[nt] = *reinterpret_cast<const float4*>(&b1[wave * 64 + nt * 16 + quad * 4]);

    __syncthreads();                      // sA dead; sH may be written

    // ---- epilogue: +b1, relu, bf16 -> sH via ds_write_b64 ----
#pragma unroll
    for (int nt = 0; nt < 4; nt++) {
#pragma unroll
        for (int mt = 0; mt < 4; mt++) {
            short4 p;
            p.x = f2bf(fmaxf(acc[nt][mt][0] + b1v[nt].x, 0.0f));
            p.y = f2bf(fmaxf(acc[nt][mt][1] + b1v[nt].y, 0.0f));
            p.z = f2bf(fmaxf(acc[nt][mt][2] + b1v[nt].z, 0.0f));
            p.w = f2bf(fmaxf(acc[nt][mt][3] + b1v[nt].w, 0.0f));
            *reinterpret_cast<short4*>(&sH[mt * 16 + l16][wave * 64 + nt * 16 + quad * 4]) = p;
        }
    }
    __syncthreads();

    // ---- GEMM2 (swapped): out^T fragment; float4 line-coalesced stores ----
    f32x4 acc2[4] = {};
#pragma unroll
    for (int kk = 0; kk < 16; kk++) {
        short8 bn = bw;
        if (kk < 15) bn = *reinterpret_cast<const short8*>(base2 + (kk + 1) * 32);
        short8 hf[4];
#pragma unroll
        for (int mt = 0; mt < 4; mt++)
            hf[mt] = *reinterpret_cast<const short8*>(&sH[mt * 16 + l16][kk * 32 + quad * 8]);
#pragma unroll
        for (int mt = 0; mt < 4; mt++)
            acc2[mt] = __builtin_amdgcn_mfma_f32_16x16x32_bf16(bw, hf[mt], acc2[mt], 0, 0, 0);
        bw = bn;
    }
    float4 b2v = *reinterpret_cast<const float4*>(&b2[wave * 16 + quad * 4]);
#pragma unroll
    for (int mt = 0; mt < 4; mt++) {
        int e = e0 + mt * 16 + l16;
        if (e < E_TOTAL) {
            float4 o;
            o.x = acc2[mt][0] + b2v.x;
            o.y = acc2[mt][1] + b2v.y;
            o.z = acc2[mt][2] + b2v.z;
            o.w = acc2[mt][3] + b2v.w;
            *reinterpret_cast<float4*>(&out[(size_t)e * DOUT + wave * 16 + quad * 4]) = o;
        }
    }
}

extern "C" void kernel_launch(void* const* d_in, const int* in_sizes, int n_in,
                              void* d_out, int out_size, void* d_ws, size_t ws_size,
                              hipStream_t stream) {
    const float* x  = (const float*)d_in[0];
    const int*   ei = (const int*)d_in[1];
    const float* ea = (const float*)d_in[2];
    const float* W1 = (const float*)d_in[3];
    const float* b1 = (const float*)d_in[4];
    const float* W2 = (const float*)d_in[5];
    const float* b2 = (const float*)d_in[6];
    float* outp = (float*)d_out;

    short* w1t = (short*)d_ws;                    // 384 KB
    short* w2t = w1t + DH * CIN;                  // 128 KB
    prep_weights<<<256, 256, 0, stream>>>(W1, W2, w1t, w2t);

    const size_t wt_bytes = (size_t)(DH * CIN + DOUT * DH) * 2;     // 512 KB
    const size_t xb_bytes = (size_t)N_NODES * DN * 2;               // 12.8 MB
    short* xb = nullptr;
    if (ws_size >= wt_bytes + xb_bytes) {
        xb = w2t + DOUT * DH;
        cvt_x<<<3125, 256, 0, stream>>>(x, xb);
    }
    edge_mlp<<<NTILE, 512, 0, stream>>>(xb, x, ei, ea, b1, b2, w1t, w2t, outp);
}

// Round 4
// 941.688 us; speedup vs baseline: 1.5792x; 1.0238x over previous
//
#include <hip/hip_runtime.h>

#define E_TOTAL 500000
#define N_NODES 50000
#define DN 128
#define CIN 384      // 2*DN + D_EDGE
#define DH 512
#define DOUT 128
#define MT 128       // edges per block (1024 thr, 16 waves, 1 block/CU)
#define NTILE 3907   // ceil(E/MT), last block 32 valid edges
#define SA_ROWB 768  // sA row bytes (bf16 384, no pad; XOR-swizzled)
#define SH_ROWB 1024 // sH row bytes (bf16 512, no pad; XOR-swizzled)
#define SO_LD 132    // sO leading dim (f32), +4 pad

typedef short short8 __attribute__((ext_vector_type(8)));
typedef float f32x4 __attribute__((ext_vector_type(4)));

__device__ inline short f2bf(float f) {
    unsigned int u = __float_as_uint(f);
    u = (u + 0x7FFFu + ((u >> 16) & 1u)) >> 16;
    return (short)u;
}

// Coalesced 32x32 LDS tile transpose: W1 [384][512] -> w1t bf16 [512][384],
// W2 [512][128] -> w2t bf16 [128][512]. Grid: 192 + 64 = 256 blocks x 256 thr.
__global__ void prep_weights(const float* __restrict__ w1,
                             const float* __restrict__ w2,
                             short* __restrict__ w1t,
                             short* __restrict__ w2t) {
    __shared__ float t[32][33];
    int b = blockIdx.x;
    const float* src; short* dst; int R, C, tr, tc;
    if (b < 192) { src = w1; dst = w1t; R = 384; C = 512; tr = b >> 4; tc = b & 15; }
    else { b -= 192; src = w2; dst = w2t; R = 512; C = 128; tr = b >> 2; tc = b & 3; }
    int lx = threadIdx.x & 31, ly = threadIdx.x >> 5;   // 32 x 8
#pragma unroll
    for (int p = 0; p < 4; p++) {
        int r = tr * 32 + p * 8 + ly;
        t[p * 8 + ly][lx] = src[(size_t)r * C + tc * 32 + lx];
    }
    __syncthreads();
#pragma unroll
    for (int p = 0; p < 4; p++) {
        int c = tc * 32 + p * 8 + ly;                   // dst row = src col
        dst[(size_t)c * R + tr * 32 + lx] = f2bf(t[lx][p * 8 + ly]);
    }
}

// x f32 [50000][128] -> bf16. 3125 blocks x 256 thr x 8 elems = 6.4M exact.
__global__ void cvt_x(const float* __restrict__ x, short* __restrict__ xb) {
    int i = blockIdx.x * 256 + threadIdx.x;
    const float4* s = reinterpret_cast<const float4*>(x) + (size_t)i * 2;
    float4 a = s[0], b = s[1];
    short8 p;
    p[0] = f2bf(a.x); p[1] = f2bf(a.y); p[2] = f2bf(a.z); p[3] = f2bf(a.w);
    p[4] = f2bf(b.x); p[5] = f2bf(b.y); p[6] = f2bf(b.z); p[7] = f2bf(b.w);
    reinterpret_cast<short8*>(xb)[i] = p;
}

// MT=128 fused edge MLP. 16 waves, 1 block/CU.
//  - GEMM1 swapped: wave w owns 128M x 32N (nt 0..1, mt 0..7), acc 64 AGPR
//  - GEMM2 swapped: wave w -> rows half=w>>3 (64), cols (w&7)*16
//  - sA/sH XOR-swizzled (byte ^= (row&7)<<4): conflict-free b128/b64 access
//  - out staged in sO (f32, LDS) -> block-linear copy = full 128B-line writes
__global__ __launch_bounds__(1024, 4) void edge_mlp(
        const short* __restrict__ xb,     // bf16 [N_NODES][128] (may be null)
        const float* __restrict__ xf,     // f32 fallback when xb == null
        const int* __restrict__ ei,       // [2][E]
        const float* __restrict__ ea,
        const float* __restrict__ b1,
        const float* __restrict__ b2,
        const short* __restrict__ w1t,    // bf16 [512][384]
        const short* __restrict__ w2t,    // bf16 [128][512]
        float* __restrict__ out) {
    // union: sA [128][768B] (96KB) / sH [128][1024B] (128KB) / sO f32[128][132] (67.6KB)
    __shared__ short sBuf[65536];         // 128 KB
    __shared__ int sIdx[2][MT];
    char* sb = (char*)sBuf;

    const int tid = threadIdx.x;
    const int wave = tid >> 6;            // 0..15
    const int lane = tid & 63;
    const int l16 = lane & 15;
    const int quad = lane >> 4;
    const int lane32 = tid & 31;
    const int g = tid >> 5;               // 0..31 gather group
    const int xorv = (l16 & 7) << 4;      // row-XOR for this lane's GEMM rows
    const int e0 = blockIdx.x * MT;

    if (tid < 2 * MT) {
        int rr = tid >> 7, r = tid & 127;
        int e = e0 + r; e = e < E_TOTAL ? e : E_TOTAL - 1;
        sIdx[rr][r] = ei[rr * E_TOTAL + e];
    }
    __syncthreads();

    // ---- batch gather: issue ALL 12 loads, then converts/stores (no spill:
    // transient ~32 VGPR, acc not live yet) ----
    short4 gx[8];
    float4 ge[4];
    if (xb) {
#pragma unroll
        for (int j = 0; j < 4; j++) {
            int r = g + 32 * j;
            gx[j]     = reinterpret_cast<const short4*>(xb + (size_t)sIdx[0][r] * DN)[lane32];
            gx[4 + j] = reinterpret_cast<const short4*>(xb + (size_t)sIdx[1][r] * DN)[lane32];
            int e = e0 + r; e = e < E_TOTAL ? e : E_TOTAL - 1;
            ge[j] = reinterpret_cast<const float4*>(ea + (size_t)e * DN)[lane32];
        }
    } else {
#pragma unroll
        for (int j = 0; j < 4; j++) {
            int r = g + 32 * j;
            float4 v0 = reinterpret_cast<const float4*>(xf + (size_t)sIdx[0][r] * DN)[lane32];
            float4 v1 = reinterpret_cast<const float4*>(xf + (size_t)sIdx[1][r] * DN)[lane32];
            short4 p0, p1;
            p0.x = f2bf(v0.x); p0.y = f2bf(v0.y); p0.z = f2bf(v0.z); p0.w = f2bf(v0.w);
            p1.x = f2bf(v1.x); p1.y = f2bf(v1.y); p1.z = f2bf(v1.z); p1.w = f2bf(v1.w);
            gx[j] = p0; gx[4 + j] = p1;
            int e = e0 + r; e = e < E_TOTAL ? e : E_TOTAL - 1;
            ge[j] = reinterpret_cast<const float4*>(ea + (size_t)e * DN)[lane32];
        }
    }
    // prefetch first w1t fragments while gathers are in flight
    const short* base1 = w1t + (size_t)(wave * 32 + l16) * CIN + quad * 8;
    short8 bb[2];
#pragma unroll
    for (int nt = 0; nt < 2; nt++)
        bb[nt] = *reinterpret_cast<const short8*>(base1 + nt * 16 * CIN);
    // swizzled sA stores (8B chunks; XOR bits 4-6 with row&7)
#pragma unroll
    for (int j = 0; j < 4; j++) {
        int r = g + 32 * j;
        int rx = (r & 7) << 4;
        char* row = sb + r * SA_ROWB;
        *reinterpret_cast<short4*>(row + (( 0 * 256 + lane32 * 8) ^ rx)) = gx[j];
        *reinterpret_cast<short4*>(row + (( 1 * 256 + lane32 * 8) ^ rx)) = gx[4 + j];
        short4 p;
        p.x = f2bf(ge[j].x); p.y = f2bf(ge[j].y); p.z = f2bf(ge[j].z); p.w = f2bf(ge[j].w);
        *reinterpret_cast<short4*>(row + (( 2 * 256 + lane32 * 8) ^ rx)) = p;
    }
    __syncthreads();

    // ---- GEMM1 (swapped): acc[nt][mt] = h^T frags, 12 k-steps ----
    f32x4 acc[2][8] = {};
    for (int k = 0; k < CIN; k += 32) {
        short8 bn[2];
        if (k + 32 < CIN) {
#pragma unroll
            for (int nt = 0; nt < 2; nt++)
                bn[nt] = *reinterpret_cast<const short8*>(base1 + nt * 16 * CIN + k + 32);
        }
        short8 a[8];
#pragma unroll
        for (int mt = 0; mt < 8; mt++) {
            int m = mt * 16 + l16;
            a[mt] = *reinterpret_cast<const short8*>(
                sb + m * SA_ROWB + ((2 * k + quad * 16) ^ xorv));
        }
#pragma unroll
        for (int nt = 0; nt < 2; nt++)
#pragma unroll
            for (int mt = 0; mt < 8; mt++)
                acc[nt][mt] = __builtin_amdgcn_mfma_f32_16x16x32_bf16(bb[nt], a[mt], acc[nt][mt], 0, 0, 0);
        if (k + 32 < CIN) {
#pragma unroll
            for (int nt = 0; nt < 2; nt++) bb[nt] = bn[nt];
        }
    }

    // prefetch w2t frag + biases into barrier shadow
    const int wn = wave & 7, half = wave >> 3;
    const short* base2 = w2t + (size_t)(wn * 16 + l16) * DH + quad * 8;
    short8 bw = *reinterpret_cast<const short8*>(base2);
    float4 b1v[2];
#pragma unroll
    for (int nt = 0; nt < 2; nt++)
        b1v[nt] = *reinterpret_cast<const float4*>(&b1[wave * 32 + nt * 16 + quad * 4]);

    __syncthreads();                      // sA dead; sH may be written

    // ---- epilogue: +b1, relu, bf16 -> sH (swizzled ds_write_b64) ----
#pragma unroll
    for (int nt = 0; nt < 2; nt++) {
#pragma unroll
        for (int mt = 0; mt < 8; mt++) {
            int m = mt * 16 + l16;
            short4 p;
            p.x = f2bf(fmaxf(acc[nt][mt][0] + b1v[nt].x, 0.0f));
            p.y = f2bf(fmaxf(acc[nt][mt][1] + b1v[nt].y, 0.0f));
            p.z = f2bf(fmaxf(acc[nt][mt][2] + b1v[nt].z, 0.0f));
            p.w = f2bf(fmaxf(acc[nt][mt][3] + b1v[nt].w, 0.0f));
            *reinterpret_cast<short4*>(
                sb + m * SH_ROWB + ((wave * 64 + nt * 32 + quad * 8) ^ xorv)) = p;
        }
    }
    __syncthreads();

    // ---- GEMM2 (swapped): wave -> rows [half*64, half*64+64), cols wn*16.. ----
    f32x4 acc2[4] = {};
#pragma unroll
    for (int kk = 0; kk < 16; kk++) {
        short8 bn = bw;
        if (kk < 15) bn = *reinterpret_cast<const short8*>(base2 + (kk + 1) * 32);
        short8 hf[4];
#pragma unroll
        for (int mt = 0; mt < 4; mt++) {
            int m = half * 64 + mt * 16 + l16;
            hf[mt] = *reinterpret_cast<const short8*>(
                sb + m * SH_ROWB + ((kk * 64 + quad * 16) ^ xorv));
        }
#pragma unroll
        for (int mt = 0; mt < 4; mt++)
            acc2[mt] = __builtin_amdgcn_mfma_f32_16x16x32_bf16(bw, hf[mt], acc2[mt], 0, 0, 0);
        bw = bn;
    }
    float4 b2v = *reinterpret_cast<const float4*>(&b2[wn * 16 + quad * 4]);
    __syncthreads();                      // sH dead; sO may be written

    // ---- stage out-tile f32 in sO, then block-linear full-line stores ----
    float (*sO)[SO_LD] = (float (*)[SO_LD])sBuf;
#pragma unroll
    for (int mt = 0; mt < 4; mt++) {
        int m = half * 64 + mt * 16 + l16;
        f32x4 o = acc2[mt];
        float* dst = &sO[m][wn * 16 + quad * 4];
        dst[0] = o[0] + b2v.x; dst[1] = o[1] + b2v.y;
        dst[2] = o[2] + b2v.z; dst[3] = o[3] + b2v.w;
    }
    __syncthreads();
#pragma unroll
    for (int it = 0; it < 4; it++) {
        int idx = tid + it * 1024;
        int row = idx >> 5, col = (idx & 31) * 4;
        int e = e0 + row;
        if (e < E_TOTAL) {
            float4 v = *reinterpret_cast<const float4*>(&sO[row][col]);
            *reinterpret_cast<float4*>(&out[(size_t)e * DOUT + col]) = v;
        }
    }
}

extern "C" void kernel_launch(void* const* d_in, const int* in_sizes, int n_in,
                              void* d_out, int out_size, void* d_ws, size_t ws_size,
                              hipStream_t stream) {
    const float* x  = (const float*)d_in[0];
    const int*   ei = (const int*)d_in[1];
    const float* ea = (const float*)d_in[2];
    const float* W1 = (const float*)d_in[3];
    const float* b1 = (const float*)d_in[4];
    const float* W2 = (const float*)d_in[5];
    const float* b2 = (const float*)d_in[6];
    float* outp = (float*)d_out;

    short* w1t = (short*)d_ws;                    // 384 KB
    short* w2t = w1t + DH * CIN;                  // 128 KB
    prep_weights<<<256, 256, 0, stream>>>(W1, W2, w1t, w2t);

    const size_t wt_bytes = (size_t)(DH * CIN + DOUT * DH) * 2;     // 512 KB
    const size_t xb_bytes = (size_t)N_NODES * DN * 2;               // 12.8 MB
    short* xbp = nullptr;
    if (ws_size >= wt_bytes + xb_bytes) {
        xbp = w2t + DOUT * DH;
        cvt_x<<<3125, 256, 0, stream>>>(x, xbp);
    }
    edge_mlp<<<NTILE, 1024, 0, stream>>>(xbp, x, ei, ea, b1, b2, w1t, w2t, outp);
}

// Round 5
// 872.666 us; speedup vs baseline: 1.7041x; 1.0791x over previous
//
#include <hip/hip_runtime.h>

#define E_TOTAL 500000
#define N_NODES 50000
#define DN 128
#define CIN 384      // 2*DN + D_EDGE
#define DH 512
#define DOUT 128
#define MT 128       // edges per block (1024 thr, 16 waves, 1 block/CU)
#define NTILE 3907   // ceil(E/MT), last block 32 valid edges
#define SEG_B 32768  // sA per-seg bytes: 128 rows x 256 B (seg-major, XOR-swizzled)
#define SH_ROWB 1024 // sH row bytes (bf16 512, XOR-swizzled)
#define SO_LD 132    // sO leading dim (f32), +4 pad

typedef short short8 __attribute__((ext_vector_type(8)));
typedef float f32x4 __attribute__((ext_vector_type(4)));

__device__ inline short f2bf(float f) {
    unsigned int u = __float_as_uint(f);
    u = (u + 0x7FFFu + ((u >> 16) & 1u)) >> 16;
    return (short)u;
}

// direct-to-LDS 16B: per-lane global src, wave-uniform LDS base (lane i -> base+i*16)
__device__ inline void gload16(const void* gsrc, void* ldst) {
    __builtin_amdgcn_global_load_lds(
        (const __attribute__((address_space(1))) unsigned int*)gsrc,
        (__attribute__((address_space(3))) unsigned int*)ldst, 16, 0, 0);
}

// Fused prep: blocks 0..255 transpose W1/W2 -> bf16; blocks 256+ convert x -> bf16.
__global__ void prep_all(const float* __restrict__ w1,
                         const float* __restrict__ w2,
                         const float* __restrict__ x,
                         short* __restrict__ w1t,
                         short* __restrict__ w2t,
                         short* __restrict__ xb) {   // xb may be null (no cvt blocks then)
    __shared__ float t[32][33];
    int b = blockIdx.x;
    if (b >= 256) {
        int i = (b - 256) * 256 + threadIdx.x;      // < 800000 exact
        const float4* s = reinterpret_cast<const float4*>(x) + (size_t)i * 2;
        float4 a = s[0], c = s[1];
        short8 p;
        p[0] = f2bf(a.x); p[1] = f2bf(a.y); p[2] = f2bf(a.z); p[3] = f2bf(a.w);
        p[4] = f2bf(c.x); p[5] = f2bf(c.y); p[6] = f2bf(c.z); p[7] = f2bf(c.w);
        reinterpret_cast<short8*>(xb)[i] = p;
        return;
    }
    const float* src; short* dst; int R, C, tr, tc;
    if (b < 192) { src = w1; dst = w1t; R = 384; C = 512; tr = b >> 4; tc = b & 15; }
    else { b -= 192; src = w2; dst = w2t; R = 512; C = 128; tr = b >> 2; tc = b & 3; }
    int lx = threadIdx.x & 31, ly = threadIdx.x >> 5;   // 32 x 8
#pragma unroll
    for (int p = 0; p < 4; p++) {
        int r = tr * 32 + p * 8 + ly;
        t[p * 8 + ly][lx] = src[(size_t)r * C + tc * 32 + lx];
    }
    __syncthreads();
#pragma unroll
    for (int p = 0; p < 4; p++) {
        int c = tc * 32 + p * 8 + ly;                   // dst row = src col
        dst[(size_t)c * R + tr * 32 + lx] = f2bf(t[lx][p * 8 + ly]);
    }
}

// MT=128 fused edge MLP, 16 waves, 1 block/CU.
// XB=1: x gathers via global_load_lds (pre-swizzled global src, linear LDS dest,
//       swizzled reads) -> zero staging VGPRs, no spill, no sIdx, no idx barrier.
// sA seg-major [seg][128][256B]; sH row-major [128][1024B]; both XOR bits 4-6
// of byte offset with (row&7)<<4. sO f32 staging -> full-line out writes.
template<int XB>
__global__ __launch_bounds__(1024, 4) void edge_mlp(
        const short* __restrict__ xb,     // bf16 [N_NODES][128] (XB=1)
        const float* __restrict__ xf,     // f32 fallback (XB=0)
        const int* __restrict__ ei,       // [2][E]
        const float* __restrict__ ea,
        const float* __restrict__ b1,
        const float* __restrict__ b2,
        const short* __restrict__ w1t,    // bf16 [512][384]
        const short* __restrict__ w2t,    // bf16 [128][512]
        float* __restrict__ out) {
    __shared__ short sBuf[65536];         // 128 KB union: sA (96KB) / sH (128KB) / sO (67.6KB)
    char* sb = (char*)sBuf;

    const int tid = threadIdx.x;
    const int wave = tid >> 6;            // 0..15
    const int lane = tid & 63;
    const int l16 = lane & 15;
    const int quad = lane >> 4;
    const int xorv = (l16 & 7) << 4;      // GEMM-read row-XOR (row ≡ l16 mod 16)
    const int e0 = blockIdx.x * MT;

    // ================= gather =================
    if (XB) {
        // --- x segs: 64 units of 4 rows; wave w owns units w, w+16, w+32, w+48.
        // lane: row = r4 + (lane>>4); 16B slot = lane&15; global col pre-swizzled.
        int idxv[4];
#pragma unroll
        for (int j = 0; j < 4; j++) {
            int u = wave + j * 16;
            int seg = u >> 5;             // 0..1
            int r4 = (u & 31) * 4;
            int e = e0 + r4 + (lane >> 4); e = e < E_TOTAL ? e : E_TOTAL - 1;
            idxv[j] = ei[seg * E_TOTAL + e];
        }
        // --- ea rows (f32->bf16 reg path): wave w owns rows w*8..w*8+7, 2 rows/instr
        const int lane32 = lane & 31, rsel = lane >> 5;
        float4 ge[4];
#pragma unroll
        for (int j = 0; j < 4; j++) {
            int r = wave * 8 + j * 2 + rsel;
            int e = e0 + r; e = e < E_TOTAL ? e : E_TOTAL - 1;
            ge[j] = reinterpret_cast<const float4*>(ea + (size_t)e * DN)[lane32];
        }
        // --- issue direct-to-LDS gathers (after idx values land)
#pragma unroll
        for (int j = 0; j < 4; j++) {
            int u = wave + j * 16;
            int seg = u >> 5;
            int r4 = (u & 31) * 4;
            int row = r4 + (lane >> 4);
            int lc = ((lane & 15) * 16) ^ ((row & 7) << 4);   // pre-swizzled global col
            const char* gsrc = (const char*)(xb + (size_t)idxv[j] * DN) + lc;
            gload16(gsrc, sb + seg * SEG_B + r4 * 256);       // wave-uniform dest
        }
        // --- prefetch first w1t frags under gather latency
        const short* base1p = w1t + (size_t)(wave * 32 + l16) * CIN + quad * 8;
        short8 bb0 = *reinterpret_cast<const short8*>(base1p);
        short8 bb1 = *reinterpret_cast<const short8*>(base1p + 16 * CIN);
        // --- ea convert + swizzled 8B stores
#pragma unroll
        for (int j = 0; j < 4; j++) {
            int r = wave * 8 + j * 2 + rsel;
            short4 p;
            p.x = f2bf(ge[j].x); p.y = f2bf(ge[j].y); p.z = f2bf(ge[j].z); p.w = f2bf(ge[j].w);
            int pc = (lane32 * 8) ^ ((r & 7) << 4);
            *reinterpret_cast<short4*>(sb + 2 * SEG_B + r * 256 + pc) = p;
        }
        __syncthreads();                  // drains vmcnt(0): gloads landed; lgkm: ea stored

        // ---- GEMM1 ----
        f32x4 acc[2][8] = {};
        short8 bb[2] = {bb0, bb1};
        for (int k = 0; k < CIN; k += 32) {
            short8 bn[2];
            if (k + 32 < CIN) {
#pragma unroll
                for (int nt = 0; nt < 2; nt++)
                    bn[nt] = *reinterpret_cast<const short8*>(base1p + nt * 16 * CIN + k + 32);
            }
            int segb = (k >> 7) * SEG_B, kk2 = 2 * (k & 127);
            short8 a[8];
#pragma unroll
            for (int mt = 0; mt < 8; mt++) {
                int m = mt * 16 + l16;
                a[mt] = *reinterpret_cast<const short8*>(
                    sb + segb + m * 256 + ((kk2 + quad * 16) ^ xorv));
            }
#pragma unroll
            for (int nt = 0; nt < 2; nt++)
#pragma unroll
                for (int mt = 0; mt < 8; mt++)
                    acc[nt][mt] = __builtin_amdgcn_mfma_f32_16x16x32_bf16(bb[nt], a[mt], acc[nt][mt], 0, 0, 0);
            if (k + 32 < CIN) { bb[0] = bn[0]; bb[1] = bn[1]; }
        }

        // prefetch w2t frag + biases into barrier shadow
        const int wn = wave & 7, half = wave >> 3;
        const short* base2 = w2t + (size_t)(wn * 16 + l16) * DH + quad * 8;
        short8 bw = *reinterpret_cast<const short8*>(base2);
        float4 b1v[2];
#pragma unroll
        for (int nt = 0; nt < 2; nt++)
            b1v[nt] = *reinterpret_cast<const float4*>(&b1[wave * 32 + nt * 16 + quad * 4]);
        __syncthreads();                  // sA dead; sH may be written

        // ---- epilogue: +b1, relu, bf16 -> sH (swizzled b64 writes) ----
#pragma unroll
        for (int nt = 0; nt < 2; nt++) {
#pragma unroll
            for (int mt = 0; mt < 8; mt++) {
                int m = mt * 16 + l16;
                short4 p;
                p.x = f2bf(fmaxf(acc[nt][mt][0] + b1v[nt].x, 0.0f));
                p.y = f2bf(fmaxf(acc[nt][mt][1] + b1v[nt].y, 0.0f));
                p.z = f2bf(fmaxf(acc[nt][mt][2] + b1v[nt].z, 0.0f));
                p.w = f2bf(fmaxf(acc[nt][mt][3] + b1v[nt].w, 0.0f));
                *reinterpret_cast<short4*>(
                    sb + m * SH_ROWB + ((wave * 64 + nt * 32 + quad * 8) ^ xorv)) = p;
            }
        }
        __syncthreads();

        // ---- GEMM2: wave -> rows [half*64 .. +64), cols wn*16.. ----
        f32x4 acc2[4] = {};
#pragma unroll
        for (int kk = 0; kk < 16; kk++) {
            short8 bn = bw;
            if (kk < 15) bn = *reinterpret_cast<const short8*>(base2 + (kk + 1) * 32);
            short8 hf[4];
#pragma unroll
            for (int mt = 0; mt < 4; mt++) {
                int m = half * 64 + mt * 16 + l16;
                hf[mt] = *reinterpret_cast<const short8*>(
                    sb + m * SH_ROWB + ((kk * 64 + quad * 16) ^ xorv));
            }
#pragma unroll
            for (int mt = 0; mt < 4; mt++)
                acc2[mt] = __builtin_amdgcn_mfma_f32_16x16x32_bf16(bw, hf[mt], acc2[mt], 0, 0, 0);
            bw = bn;
        }
        float4 b2v = *reinterpret_cast<const float4*>(&b2[wn * 16 + quad * 4]);
        __syncthreads();                  // sH dead; sO may be written

        // ---- sO staging -> block-linear full-line out writes ----
        float (*sO)[SO_LD] = (float (*)[SO_LD])sBuf;
#pragma unroll
        for (int mt = 0; mt < 4; mt++) {
            int m = half * 64 + mt * 16 + l16;
            float* dst = &sO[m][wn * 16 + quad * 4];
            dst[0] = acc2[mt][0] + b2v.x; dst[1] = acc2[mt][1] + b2v.y;
            dst[2] = acc2[mt][2] + b2v.z; dst[3] = acc2[mt][3] + b2v.w;
        }
        __syncthreads();
#pragma unroll
        for (int it = 0; it < 4; it++) {
            int idx = tid + it * 1024;
            int row = idx >> 5, col = (idx & 31) * 4;
            int e = e0 + row;
            if (e < E_TOTAL) {
                float4 v = *reinterpret_cast<const float4*>(&sO[row][col]);
                *reinterpret_cast<float4*>(&out[(size_t)e * DOUT + col]) = v;
            }
        }
    } else {
        // ===== XB=0 fallback: f32 gathers, reg path batched in halves (no spill) =====
        int* sIdx = (int*)(sb + 122880);  // beyond sA's 96KB, dead before sH epilogue
        if (tid < 2 * MT) {
            int rr = tid >> 7, r = tid & 127;
            int e = e0 + r; e = e < E_TOTAL ? e : E_TOTAL - 1;
            sIdx[rr * MT + r] = ei[rr * E_TOTAL + e];
        }
        __syncthreads();
        const int lane32 = lane & 31;
        const int g = tid >> 5;           // 0..31
#pragma unroll
        for (int h2 = 0; h2 < 2; h2++) {
            float4 v0[2], v1[2], ve[2];
#pragma unroll
            for (int jj = 0; jj < 2; jj++) {
                int r = g + 32 * (h2 * 2 + jj);
                v0[jj] = reinterpret_cast<const float4*>(xf + (size_t)sIdx[r] * DN)[lane32];
                v1[jj] = reinterpret_cast<const float4*>(xf + (size_t)sIdx[MT + r] * DN)[lane32];
                int e = e0 + r; e = e < E_TOTAL ? e : E_TOTAL - 1;
                ve[jj] = reinterpret_cast<const float4*>(ea + (size_t)e * DN)[lane32];
            }
#pragma unroll
            for (int jj = 0; jj < 2; jj++) {
                int r = g + 32 * (h2 * 2 + jj);
                int rx = (r & 7) << 4;
                int pc0 = (lane32 & 15) * 16 + (lane32 >> 4) * 8;   // 8B within 16B slots? no:
                (void)pc0;
                int pc = (lane32 * 8) ^ rx;   // logical byte lane32*8, 8B store
                short4 p0, p1, pe;
                p0.x = f2bf(v0[jj].x); p0.y = f2bf(v0[jj].y); p0.z = f2bf(v0[jj].z); p0.w = f2bf(v0[jj].w);
                p1.x = f2bf(v1[jj].x); p1.y = f2bf(v1[jj].y); p1.z = f2bf(v1[jj].z); p1.w = f2bf(v1[jj].w);
                pe.x = f2bf(ve[jj].x); pe.y = f2bf(ve[jj].y); pe.z = f2bf(ve[jj].z); pe.w = f2bf(ve[jj].w);
                *reinterpret_cast<short4*>(sb + 0 * SEG_B + r * 256 + pc) = p0;
                *reinterpret_cast<short4*>(sb + 1 * SEG_B + r * 256 + pc) = p1;
                *reinterpret_cast<short4*>(sb + 2 * SEG_B + r * 256 + pc) = pe;
            }
        }
        const short* base1p = w1t + (size_t)(wave * 32 + l16) * CIN + quad * 8;
        short8 bb0 = *reinterpret_cast<const short8*>(base1p);
        short8 bb1 = *reinterpret_cast<const short8*>(base1p + 16 * CIN);
        __syncthreads();

        f32x4 acc[2][8] = {};
        short8 bb[2] = {bb0, bb1};
        for (int k = 0; k < CIN; k += 32) {
            short8 bn[2];
            if (k + 32 < CIN) {
#pragma unroll
                for (int nt = 0; nt < 2; nt++)
                    bn[nt] = *reinterpret_cast<const short8*>(base1p + nt * 16 * CIN + k + 32);
            }
            int segb = (k >> 7) * SEG_B, kk2 = 2 * (k & 127);
            short8 a[8];
#pragma unroll
            for (int mt = 0; mt < 8; mt++) {
                int m = mt * 16 + l16;
                a[mt] = *reinterpret_cast<const short8*>(
                    sb + segb + m * 256 + ((kk2 + quad * 16) ^ xorv));
            }
#pragma unroll
            for (int nt = 0; nt < 2; nt++)
#pragma unroll
                for (int mt = 0; mt < 8; mt++)
                    acc[nt][mt] = __builtin_amdgcn_mfma_f32_16x16x32_bf16(bb[nt], a[mt], acc[nt][mt], 0, 0, 0);
            if (k + 32 < CIN) { bb[0] = bn[0]; bb[1] = bn[1]; }
        }
        const int wn = wave & 7, half = wave >> 3;
        const short* base2 = w2t + (size_t)(wn * 16 + l16) * DH + quad * 8;
        short8 bw = *reinterpret_cast<const short8*>(base2);
        float4 b1v[2];
#pragma unroll
        for (int nt = 0; nt < 2; nt++)
            b1v[nt] = *reinterpret_cast<const float4*>(&b1[wave * 32 + nt * 16 + quad * 4]);
        __syncthreads();
#pragma unroll
        for (int nt = 0; nt < 2; nt++) {
#pragma unroll
            for (int mt = 0; mt < 8; mt++) {
                int m = mt * 16 + l16;
                short4 p;
                p.x = f2bf(fmaxf(acc[nt][mt][0] + b1v[nt].x, 0.0f));
                p.y = f2bf(fmaxf(acc[nt][mt][1] + b1v[nt].y, 0.0f));
                p.z = f2bf(fmaxf(acc[nt][mt][2] + b1v[nt].z, 0.0f));
                p.w = f2bf(fmaxf(acc[nt][mt][3] + b1v[nt].w, 0.0f));
                *reinterpret_cast<short4*>(
                    sb + m * SH_ROWB + ((wave * 64 + nt * 32 + quad * 8) ^ xorv)) = p;
            }
        }
        __syncthreads();
        f32x4 acc2[4] = {};
#pragma unroll
        for (int kk = 0; kk < 16; kk++) {
            short8 bn = bw;
            if (kk < 15) bn = *reinterpret_cast<const short8*>(base2 + (kk + 1) * 32);
            short8 hf[4];
#pragma unroll
            for (int mt = 0; mt < 4; mt++) {
                int m = half * 64 + mt * 16 + l16;
                hf[mt] = *reinterpret_cast<const short8*>(
                    sb + m * SH_ROWB + ((kk * 64 + quad * 16) ^ xorv));
            }
#pragma unroll
            for (int mt = 0; mt < 4; mt++)
                acc2[mt] = __builtin_amdgcn_mfma_f32_16x16x32_bf16(bw, hf[mt], acc2[mt], 0, 0, 0);
            bw = bn;
        }
        float4 b2v = *reinterpret_cast<const float4*>(&b2[wn * 16 + quad * 4]);
        __syncthreads();
        float (*sO)[SO_LD] = (float (*)[SO_LD])sBuf;
#pragma unroll
        for (int mt = 0; mt < 4; mt++) {
            int m = half * 64 + mt * 16 + l16;
            float* dst = &sO[m][wn * 16 + quad * 4];
            dst[0] = acc2[mt][0] + b2v.x; dst[1] = acc2[mt][1] + b2v.y;
            dst[2] = acc2[mt][2] + b2v.z; dst[3] = acc2[mt][3] + b2v.w;
        }
        __syncthreads();
#pragma unroll
        for (int it = 0; it < 4; it++) {
            int idx = tid + it * 1024;
            int row = idx >> 5, col = (idx & 31) * 4;
            int e = e0 + row;
            if (e < E_TOTAL) {
                float4 v = *reinterpret_cast<const float4*>(&sO[row][col]);
                *reinterpret_cast<float4*>(&out[(size_t)e * DOUT + col]) = v;
            }
        }
    }
}

extern "C" void kernel_launch(void* const* d_in, const int* in_sizes, int n_in,
                              void* d_out, int out_size, void* d_ws, size_t ws_size,
                              hipStream_t stream) {
    const float* x  = (const float*)d_in[0];
    const int*   ei = (const int*)d_in[1];
    const float* ea = (const float*)d_in[2];
    const float* W1 = (const float*)d_in[3];
    const float* b1 = (const float*)d_in[4];
    const float* W2 = (const float*)d_in[5];
    const float* b2 = (const float*)d_in[6];
    float* outp = (float*)d_out;

    short* w1t = (short*)d_ws;                    // 384 KB
    short* w2t = w1t + DH * CIN;                  // 128 KB

    const size_t wt_bytes = (size_t)(DH * CIN + DOUT * DH) * 2;     // 512 KB
    const size_t xb_bytes = (size_t)N_NODES * DN * 2;               // 12.8 MB
    const bool has_xb = ws_size >= wt_bytes + xb_bytes;
    short* xbp = has_xb ? (w2t + DOUT * DH) : nullptr;

    prep_all<<<has_xb ? 3381 : 256, 256, 0, stream>>>(W1, W2, x, w1t, w2t, xbp);

    if (has_xb)
        edge_mlp<1><<<NTILE, 1024, 0, stream>>>(xbp, x, ei, ea, b1, b2, w1t, w2t, outp);
    else
        edge_mlp<0><<<NTILE, 1024, 0, stream>>>(nullptr, x, ei, ea, b1, b2, w1t, w2t, outp);
}